// Round 2
// baseline (378.602 us; speedup 1.0000x reference)
//
#include <hip/hip_runtime.h>
#include <math.h>

#define B 8
#define S 1024
#define D 1024
#define F 3584

#define NBLK 256   // grid size; <= CU count -> co-residency guaranteed by capacity
#define KSV 64     // split-K chunks for 1024x1024 matvecs (16 rows each)
#define CHV 16
#define KS5 16     // gate/up split-K chunks (64 rows each)
#define CH5 64
#define KS6 112    // down split-K chunks (32 rows each)
#define CH6 32

#define LD4(p) (*(const float4*)(p))
#define FMA4(A, s, W) { (A).x += (s)*(W).x; (A).y += (s)*(W).y; (A).z += (s)*(W).z; (A).w += (s)*(W).w; }

// 8-row FMA step for token-batch bb against weight regs w0..w7 (k = koff..koff+7)
#define BB8(bb, ACC, XS, CH, koff) { \
  float4 xa = LD4((XS) + (bb)*(CH) + (koff)); \
  float4 xb = LD4((XS) + (bb)*(CH) + (koff) + 4); \
  FMA4(ACC, xa.x, w0); FMA4(ACC, xa.y, w1); FMA4(ACC, xa.z, w2); FMA4(ACC, xa.w, w3); \
  FMA4(ACC, xb.x, w4); FMA4(ACC, xb.y, w5); FMA4(ACC, xb.z, w6); FMA4(ACC, xb.w, w7); }

#define ALL8(XS, CH, koff) \
  BB8(0, acc0, XS, CH, koff) BB8(1, acc1, XS, CH, koff) \
  BB8(2, acc2, XS, CH, koff) BB8(3, acc3, XS, CH, koff) \
  BB8(4, acc4, XS, CH, koff) BB8(5, acc5, XS, CH, koff) \
  BB8(6, acc6, XS, CH, koff) BB8(7, acc7, XS, CH, koff)

// ---------------- block-wide sum for 256-thread blocks ----------------
__device__ __forceinline__ float block_sum256(float v, volatile float* buf) {
  #pragma unroll
  for (int o = 32; o; o >>= 1) v += __shfl_down(v, o);   // wave64 reduce
  __syncthreads();
  if ((threadIdx.x & 63) == 0) buf[threadIdx.x >> 6] = v;
  __syncthreads();
  return buf[0] + buf[1] + buf[2] + buf[3];
}

// ---------------- grid barrier: monotonic counter, agent scope ----------------
// bar is memset to 0 on the stream before every launch (ws is poisoned between
// iterations, so we never rely on its prior contents). 256 blocks are always
// co-resident (grid <= CU count, any VGPR count allows >=1 block/CU), so the
// spin cannot deadlock. Release on the add publishes this block's stores;
// ACQUIRE on the spin-load invalidates stale caches before consuming.
__device__ __forceinline__ void gsync(unsigned* bar, unsigned tgt) {
  __syncthreads();
  if (threadIdx.x == 0) {
    __hip_atomic_fetch_add(bar, 1u, __ATOMIC_RELEASE, __HIP_MEMORY_SCOPE_AGENT);
    while (__hip_atomic_load(bar, __ATOMIC_ACQUIRE, __HIP_MEMORY_SCOPE_AGENT) < tgt)
      __builtin_amdgcn_s_sleep(4);
  }
  __syncthreads();
}

// 16-row x 1024-col x 8-token matvec step (phases 2 and 3).
// Wp already offset to (chunk row 0, col j). Pout already offset to chunk base.
__device__ __forceinline__ void mv16(const float4* __restrict__ Wp,
                                     float* __restrict__ Pout,
                                     const float* xs, int j) {
  const int st = D / 4;
  float4 acc0 = {0,0,0,0}, acc1 = {0,0,0,0}, acc2 = {0,0,0,0}, acc3 = {0,0,0,0};
  float4 acc4 = {0,0,0,0}, acc5 = {0,0,0,0}, acc6 = {0,0,0,0}, acc7 = {0,0,0,0};
  float4 w0 = Wp[0*st], w1 = Wp[1*st], w2 = Wp[2*st], w3 = Wp[3*st];
  float4 w4 = Wp[4*st], w5 = Wp[5*st], w6 = Wp[6*st], w7 = Wp[7*st];
  float4 v0 = Wp[8*st], v1 = Wp[9*st], v2 = Wp[10*st], v3 = Wp[11*st];
  float4 v4 = Wp[12*st], v5 = Wp[13*st], v6 = Wp[14*st], v7 = Wp[15*st];
  ALL8(xs, CHV, 0);
  w0 = v0; w1 = v1; w2 = v2; w3 = v3; w4 = v4; w5 = v5; w6 = v6; w7 = v7;
  ALL8(xs, CHV, 8);
  *(float4*)(Pout + 0*(size_t)D + j) = acc0;
  *(float4*)(Pout + 1*(size_t)D + j) = acc1;
  *(float4*)(Pout + 2*(size_t)D + j) = acc2;
  *(float4*)(Pout + 3*(size_t)D + j) = acc3;
  *(float4*)(Pout + 4*(size_t)D + j) = acc4;
  *(float4*)(Pout + 5*(size_t)D + j) = acc5;
  *(float4*)(Pout + 6*(size_t)D + j) = acc6;
  *(float4*)(Pout + 7*(size_t)D + j) = acc7;
}

// One fused kernel: 8 phases, 7 grid barriers. Eliminates 8 serial launches.
__global__ __launch_bounds__(256, 1) void k_fused(
    const float* __restrict__ hs, const float* __restrict__ ln1,
    const float* __restrict__ vw, const float* __restrict__ ow,
    const float* __restrict__ ln2, const float* __restrict__ rw,
    const float* __restrict__ gw, const float* __restrict__ uw,
    const float* __restrict__ dw, const float* __restrict__ flw,
    const float* __restrict__ sw, float* __restrict__ out,
    float* __restrict__ wsf, unsigned* __restrict__ bar) {
  __shared__ float xs[512];
  __shared__ float rbuf[4];
  const int tid = threadIdx.x;
  const int bid = blockIdx.x;

  float* h1    = wsf;                                   // [8][1024]
  float* Vp    = wsf + 8192;                            // [KSV][8][1024]
  float* Op    = Vp + (size_t)KSV * 8 * D;              // [KSV][8][1024]
  float* xr    = Op + (size_t)KSV * 8 * D;              // [8][1024]
  float* h2    = xr + 8192;                             // [8][1024]
  float* tw8   = h2 + 8192;                             // [8]
  int*   sel8  = (int*)(tw8 + 8);                       // [8]
  float* Pgu   = tw8 + 16;                              // [KS5][4][8][F]
  float* Dp    = Pgu + (size_t)KS5 * 4 * 8 * F;         // [KS6][2][8][1024]
  float* x2    = Dp + (size_t)KS6 * 2 * 8 * D;          // [8][1024]
  float* psq   = x2 + 8192;                             // [32]
  float* dummy = psq + 32;                              // [256] anti-DCE sink

  // ---- phase 1: h1[b] = rmsnorm(hidden[b,0,:], ln1) ----
  if (bid < 8) {
    int idx = tid * 4;
    float4 x = LD4(hs + (size_t)bid * S * D + idx);
    float ss = x.x*x.x + x.y*x.y + x.z*x.z + x.w*x.w;
    float tot = block_sum256(ss, rbuf);
    float sc = rsqrtf(tot * (1.f / (float)D) + 1e-6f);
    float4 wv = LD4(ln1 + idx);
    float4 o;
    o.x = x.x*sc*wv.x; o.y = x.y*sc*wv.y; o.z = x.z*sc*wv.z; o.w = x.w*sc*wv.w;
    *(float4*)(h1 + bid * D + idx) = o;
  }
  gsync(bar, NBLK * 1);

  float4 pref = {0,0,0,0};   // LLC-prefetch accumulator (idle blocks, phases 2-3)

  // ---- phase 2: Vp split-K partials of h1 @ v_w (64 blocks) ----
  if (bid < KSV) {
    int i0 = bid * CHV;
    if (tid < 128) xs[tid] = h1[(tid >> 4) * D + i0 + (tid & 15)];
    __syncthreads();
    int j = tid * 4;
    mv16((const float4*)(vw + (size_t)i0 * D + j), Vp + (size_t)bid * 8 * D, xs, j);
  } else {
    // 192 idle blocks: stream 64 KB each of gate_w into LLC (HBM otherwise idle)
    const float4* src = (const float4*)gw + (size_t)(bid - 64) * 4096 + tid;
    #pragma unroll
    for (int t = 0; t < 16; t++) {
      float4 v = src[(size_t)t * 256];
      pref.x += v.x; pref.y += v.y; pref.z += v.z; pref.w += v.w;
    }
  }
  gsync(bar, NBLK * 2);

  // ---- phase 3: reduce Vp slice -> xs, then Op partials of v0 @ o_w ----
  if (bid < KSV) {
    int i0 = bid * CHV;
    if (tid < 128) {
      int bb = tid >> 4, ii = tid & 15;
      float s = 0.f;
      #pragma unroll 8
      for (int p = 0; p < KSV; p++) s += Vp[((size_t)p * 8 + bb) * D + i0 + ii];
      xs[bb * 16 + ii] = s;
    }
    __syncthreads();
    int j = tid * 4;
    mv16((const float4*)(ow + (size_t)i0 * D + j), Op + (size_t)bid * 8 * D, xs, j);
  } else {
    // 64 KB each of up_w into LLC
    const float4* src = (const float4*)uw + (size_t)(bid - 64) * 4096 + tid;
    #pragma unroll
    for (int t = 0; t < 16; t++) {
      float4 v = src[(size_t)t * 256];
      pref.x += v.x; pref.y += v.y; pref.z += v.z; pref.w += v.w;
    }
    float tchk = pref.x + pref.y + pref.z + pref.w;
    if (tchk > 1e30f) dummy[bid] = tchk;   // opaque: keeps prefetch loads live
  }
  gsync(bar, NBLK * 3);

  // ---- phase 4: xr = hs + attn_out; h2 = rmsnorm(xr, ln2); router top-1 ----
  if (bid < 8) {
    int idx = tid * 4;
    float4 x = LD4(hs + (size_t)bid * S * D + idx);
    #pragma unroll 8
    for (int p = 0; p < KSV; p++) {
      float4 v = LD4(Op + ((size_t)p * 8 + bid) * D + idx);
      x.x += v.x; x.y += v.y; x.z += v.z; x.w += v.w;
    }
    *(float4*)(xr + bid * D + idx) = x;
    float ss = x.x*x.x + x.y*x.y + x.z*x.z + x.w*x.w;
    float tot = block_sum256(ss, rbuf);
    float sc = rsqrtf(tot * (1.f / (float)D) + 1e-6f);
    float4 wv = LD4(ln2 + idx);
    float4 h;
    h.x = x.x*sc*wv.x; h.y = x.y*sc*wv.y; h.z = x.z*sc*wv.z; h.w = x.w*sc*wv.w;
    *(float4*)(h2 + bid * D + idx) = h;
    float r0 = h.x * rw[idx * 2]     + h.y * rw[(idx + 1) * 2] +
               h.z * rw[(idx + 2) * 2] + h.w * rw[(idx + 3) * 2];
    float r1 = h.x * rw[idx * 2 + 1]     + h.y * rw[(idx + 1) * 2 + 1] +
               h.z * rw[(idx + 2) * 2 + 1] + h.w * rw[(idx + 3) * 2 + 1];
    r0 = block_sum256(r0, rbuf);
    r1 = block_sum256(r1, rbuf);
    if (tid == 0) {
      float m = fmaxf(r0, r1);
      float e0 = __expf(r0 - m), e1 = __expf(r1 - m);
      float inv = 1.f / (e0 + e1);
      float p0 = e0 * inv, p1 = e1 * inv;
      tw8[bid] = fmaxf(p0, p1);
      sel8[bid] = (p1 > p0) ? 1 : 0;
    }
  }
  gsync(bar, NBLK * 4);

  // ---- phase 5: gate/up split-K partials (224 blocks: 14 col-tiles x 16 k-chunks) ----
  if (bid < 14 * KS5) {
    int kc = bid & 15, colt = bid >> 4;
    int i0 = kc * CH5;
    { int bb = tid >> 6, r = tid & 63;
      xs[tid]       = h2[bb * D + i0 + r];
      xs[tid + 256] = h2[(bb + 4) * D + i0 + r]; }
    __syncthreads();
    int c = colt * 1024 + tid * 4;     // flattened col over 4 matrices (4*F)
    int m = c / F;                     // 0:gate e0, 1:gate e1, 2:up e0, 3:up e1
    int j = c - m * F;
    const float* base = (m < 2 ? gw : uw) + (size_t)(m & 1) * D * F;
    const float4* Wp = (const float4*)(base + (size_t)i0 * F + j);
    const int st = F / 4;
    float4 acc0 = {0,0,0,0}, acc1 = {0,0,0,0}, acc2 = {0,0,0,0}, acc3 = {0,0,0,0};
    float4 acc4 = {0,0,0,0}, acc5 = {0,0,0,0}, acc6 = {0,0,0,0}, acc7 = {0,0,0,0};
    float4 w0 = Wp[0*st], w1 = Wp[1*st], w2 = Wp[2*st], w3 = Wp[3*st];
    float4 w4 = Wp[4*st], w5 = Wp[5*st], w6 = Wp[6*st], w7 = Wp[7*st];
    Wp += 8 * st;
    #pragma unroll
    for (int t = 0; t < CH5 / 8 - 1; t++) {
      float4 n0 = Wp[0*st], n1 = Wp[1*st], n2 = Wp[2*st], n3 = Wp[3*st];
      float4 n4 = Wp[4*st], n5 = Wp[5*st], n6 = Wp[6*st], n7 = Wp[7*st];
      Wp += 8 * st;
      ALL8(xs, CH5, t * 8);
      w0 = n0; w1 = n1; w2 = n2; w3 = n3; w4 = n4; w5 = n5; w6 = n6; w7 = n7;
    }
    ALL8(xs, CH5, CH5 - 8);
    #define GU_ST(bb, ACC) \
      *(float4*)(Pgu + (((size_t)kc * 4 + m) * 8 + (bb)) * F + j) = ACC;
    GU_ST(0, acc0) GU_ST(1, acc1) GU_ST(2, acc2) GU_ST(3, acc3)
    GU_ST(4, acc4) GU_ST(5, acc5) GU_ST(6, acc6) GU_ST(7, acc7)
    #undef GU_ST
  }
  gsync(bar, NBLK * 5);

  // ---- phase 6: silu-reduce Pgu slice -> xs, then down split-K partials ----
  if (bid < 2 * KS6) {
    int e = bid & 1, ch = bid >> 1, i0 = ch * CH6;
    { int bb = tid >> 5, ii = tid & 31;
      float ga = 0.f, ua = 0.f;
      #pragma unroll
      for (int kc = 0; kc < KS5; kc++) {
        ga += Pgu[(((size_t)kc * 4 + e)     * 8 + bb) * F + i0 + ii];
        ua += Pgu[(((size_t)kc * 4 + 2 + e) * 8 + bb) * F + i0 + ii];
      }
      xs[bb * CH6 + ii] = (ga / (1.f + __expf(-ga))) * ua; }
    __syncthreads();
    int j = tid * 4;
    const float4* Wp = (const float4*)(dw + (size_t)e * F * D + (size_t)i0 * D + j);
    const int st = D / 4;
    float4 acc0 = {0,0,0,0}, acc1 = {0,0,0,0}, acc2 = {0,0,0,0}, acc3 = {0,0,0,0};
    float4 acc4 = {0,0,0,0}, acc5 = {0,0,0,0}, acc6 = {0,0,0,0}, acc7 = {0,0,0,0};
    float4 w0 = Wp[0*st], w1 = Wp[1*st], w2 = Wp[2*st], w3 = Wp[3*st];
    float4 w4 = Wp[4*st], w5 = Wp[5*st], w6 = Wp[6*st], w7 = Wp[7*st];
    Wp += 8 * st;
    #pragma unroll
    for (int t = 0; t < CH6 / 8 - 1; t++) {
      float4 n0 = Wp[0*st], n1 = Wp[1*st], n2 = Wp[2*st], n3 = Wp[3*st];
      float4 n4 = Wp[4*st], n5 = Wp[5*st], n6 = Wp[6*st], n7 = Wp[7*st];
      Wp += 8 * st;
      ALL8(xs, CH6, t * 8);
      w0 = n0; w1 = n1; w2 = n2; w3 = n3; w4 = n4; w5 = n5; w6 = n6; w7 = n7;
    }
    ALL8(xs, CH6, CH6 - 8);
    #define DN_ST(bb, ACC) \
      *(float4*)(Dp + (((size_t)ch * 2 + e) * 8 + (bb)) * D + j) = ACC;
    DN_ST(0, acc0) DN_ST(1, acc1) DN_ST(2, acc2) DN_ST(3, acc3)
    DN_ST(4, acc4) DN_ST(5, acc5) DN_ST(6, acc6) DN_ST(7, acc7)
    #undef DN_ST
  }
  gsync(bar, NBLK * 6);

  // ---- phase 7: x2 = xr + top_w * sum_p Dp[p][sel]; per-block partial sumsq ----
  if (bid < 32) {
    int gid = bid * 256 + tid;
    int bb = gid >> 10, col = gid & 1023;
    int e = sel8[bb];
    float tw = tw8[bb];
    float s = 0.f;
    #pragma unroll 8
    for (int p = 0; p < KS6; p++) s += Dp[(((size_t)p * 2 + e) * 8 + bb) * D + col];
    float v = xr[bb * D + col] + tw * s;
    x2[gid] = v;
    float ps = block_sum256(v * v, rbuf);
    if (tid == 0) psq[bid] = ps;       // bid == bb*4 + quarter
  }
  gsync(bar, NBLK * 7);

  // ---- phase 8: final rmsnorm + score head ----
  if (bid < 8) {
    int idx = tid * 4;
    float tot = psq[bid * 4] + psq[bid * 4 + 1] + psq[bid * 4 + 2] + psq[bid * 4 + 3];
    float sc = rsqrtf(tot * (1.f / (float)D) + 1e-6f);
    float4 x = LD4(x2 + bid * D + idx);
    float4 wv = LD4(flw + idx);
    float n0 = x.x*sc*wv.x, n1 = x.y*sc*wv.y, n2 = x.z*sc*wv.z, n3 = x.w*sc*wv.w;
    float l0 = n0 * sw[idx * 2]     + n1 * sw[(idx + 1) * 2] +
               n2 * sw[(idx + 2) * 2] + n3 * sw[(idx + 3) * 2];
    float l1 = n0 * sw[idx * 2 + 1]     + n1 * sw[(idx + 1) * 2 + 1] +
               n2 * sw[(idx + 2) * 2 + 1] + n3 * sw[(idx + 3) * 2 + 1];
    l0 = block_sum256(l0, rbuf);
    l1 = block_sum256(l1, rbuf);
    if (tid == 0) { out[bid * 2 + 0] = l0; out[bid * 2 + 1] = l1; }
  }
}

extern "C" void kernel_launch(void* const* d_in, const int* in_sizes, int n_in,
                              void* d_out, int out_size, void* d_ws, size_t ws_size,
                              hipStream_t stream) {
  const float* hs  = (const float*)d_in[0];
  const float* ln1 = (const float*)d_in[1];
  // d_in[2]=q_w, d_in[3]=k_w: dead — token-0 causal attention only needs V.
  const float* vw  = (const float*)d_in[4];
  const float* ow  = (const float*)d_in[5];
  const float* ln2 = (const float*)d_in[6];
  const float* rw  = (const float*)d_in[7];
  const float* gw  = (const float*)d_in[8];
  const float* uw  = (const float*)d_in[9];
  const float* dw  = (const float*)d_in[10];
  const float* flw = (const float*)d_in[11];
  const float* sw  = (const float*)d_in[12];

  unsigned* bar = (unsigned*)d_ws;          // first 256 B: grid-barrier counter
  float* wsf = (float*)d_ws + 64;           // data region (~19 MB used)

  // ws is poisoned between iterations: the barrier counter must be zeroed on
  // the stream every launch (graph-captured as a memset node).
  (void)hipMemsetAsync(d_ws, 0, 256, stream);
  hipLaunchKernelGGL(k_fused, dim3(NBLK), dim3(256), 0, stream,
                     hs, ln1, vw, ow, ln2, rw, gw, uw, dw, flw, sw,
                     (float*)d_out, wsf, bar);
}

// Round 3
// 295.326 us; speedup vs baseline: 1.2820x; 1.2820x over previous
//
#include <hip/hip_runtime.h>
#include <math.h>

#define B 8
#define S 1024
#define D 1024
#define F 3584

#define NBLK 256   // grid size; <= CU count -> co-residency guaranteed by capacity
#define KSV 64     // split-K chunks for 1024x1024 matvecs (16 rows each)
#define CHV 16
#define KS5 16     // gate/up split-K chunks (64 rows each)
#define CH5 64
#define KS6 112    // down split-K chunks (32 rows each)
#define CH6 32

#define LD4(p) (*(const float4*)(p))
#define FMA4(A, s, W) { (A).x += (s)*(W).x; (A).y += (s)*(W).y; (A).z += (s)*(W).z; (A).w += (s)*(W).w; }

// 8-row FMA step for token-batch bb against weight regs w0..w7 (k = koff..koff+7)
#define BB8(bb, ACC, XS, CH, koff) { \
  float4 xa = LD4((XS) + (bb)*(CH) + (koff)); \
  float4 xb = LD4((XS) + (bb)*(CH) + (koff) + 4); \
  FMA4(ACC, xa.x, w0); FMA4(ACC, xa.y, w1); FMA4(ACC, xa.z, w2); FMA4(ACC, xa.w, w3); \
  FMA4(ACC, xb.x, w4); FMA4(ACC, xb.y, w5); FMA4(ACC, xb.z, w6); FMA4(ACC, xb.w, w7); }

#define ALL8(XS, CH, koff) \
  BB8(0, acc0, XS, CH, koff) BB8(1, acc1, XS, CH, koff) \
  BB8(2, acc2, XS, CH, koff) BB8(3, acc3, XS, CH, koff) \
  BB8(4, acc4, XS, CH, koff) BB8(5, acc5, XS, CH, koff) \
  BB8(6, acc6, XS, CH, koff) BB8(7, acc7, XS, CH, koff)

// ---------------- block-wide sum for 256-thread blocks ----------------
__device__ __forceinline__ float block_sum256(float v, volatile float* buf) {
  #pragma unroll
  for (int o = 32; o; o >>= 1) v += __shfl_down(v, o);   // wave64 reduce
  __syncthreads();
  if ((threadIdx.x & 63) == 0) buf[threadIdx.x >> 6] = v;
  __syncthreads();
  return buf[0] + buf[1] + buf[2] + buf[3];
}

// ---------------- grid barrier: monotonic counter, agent scope ----------------
// CRITICAL (round-3 fix): the spin poll is RELAXED. An agent-scope ACQUIRE
// load emits cache-invalidate ops before the load; polling with acquire had
// ~200 blocks firing invalidates into the per-XCD L2s continuously, throttling
// the working blocks' streaming loads to ~350 GB/s (round-2 post-mortem).
// Relaxed atomic loads still bypass stale caches (scope flags), so progress is
// observed. ONE acquire load after the spin synchronizes with the entire
// release sequence of arriving fetch_adds (C++ release-sequence rule), giving
// the same visibility guarantee as round 2's acquire-in-loop.
__device__ __forceinline__ void gsync(unsigned* bar, unsigned tgt) {
  __syncthreads();
  if (threadIdx.x == 0) {
    __hip_atomic_fetch_add(bar, 1u, __ATOMIC_RELEASE, __HIP_MEMORY_SCOPE_AGENT);
    while (__hip_atomic_load(bar, __ATOMIC_RELAXED, __HIP_MEMORY_SCOPE_AGENT) < tgt)
      __builtin_amdgcn_s_sleep(1);
    (void)__hip_atomic_load(bar, __ATOMIC_ACQUIRE, __HIP_MEMORY_SCOPE_AGENT);
  }
  __syncthreads();
}

// 16-row x 1024-col x 8-token matvec step (phases 2 and 3).
// Wp already offset to (chunk row 0, col j). Pout already offset to chunk base.
__device__ __forceinline__ void mv16(const float4* __restrict__ Wp,
                                     float* __restrict__ Pout,
                                     const float* xs, int j) {
  const int st = D / 4;
  float4 acc0 = {0,0,0,0}, acc1 = {0,0,0,0}, acc2 = {0,0,0,0}, acc3 = {0,0,0,0};
  float4 acc4 = {0,0,0,0}, acc5 = {0,0,0,0}, acc6 = {0,0,0,0}, acc7 = {0,0,0,0};
  float4 w0 = Wp[0*st], w1 = Wp[1*st], w2 = Wp[2*st], w3 = Wp[3*st];
  float4 w4 = Wp[4*st], w5 = Wp[5*st], w6 = Wp[6*st], w7 = Wp[7*st];
  float4 v0 = Wp[8*st], v1 = Wp[9*st], v2 = Wp[10*st], v3 = Wp[11*st];
  float4 v4 = Wp[12*st], v5 = Wp[13*st], v6 = Wp[14*st], v7 = Wp[15*st];
  ALL8(xs, CHV, 0);
  w0 = v0; w1 = v1; w2 = v2; w3 = v3; w4 = v4; w5 = v5; w6 = v6; w7 = v7;
  ALL8(xs, CHV, 8);
  *(float4*)(Pout + 0*(size_t)D + j) = acc0;
  *(float4*)(Pout + 1*(size_t)D + j) = acc1;
  *(float4*)(Pout + 2*(size_t)D + j) = acc2;
  *(float4*)(Pout + 3*(size_t)D + j) = acc3;
  *(float4*)(Pout + 4*(size_t)D + j) = acc4;
  *(float4*)(Pout + 5*(size_t)D + j) = acc5;
  *(float4*)(Pout + 6*(size_t)D + j) = acc6;
  *(float4*)(Pout + 7*(size_t)D + j) = acc7;
}

// One fused kernel: 8 phases, 7 grid barriers. Eliminates 8 serial launches.
__global__ __launch_bounds__(256, 1) void k_fused(
    const float* __restrict__ hs, const float* __restrict__ ln1,
    const float* __restrict__ vw, const float* __restrict__ ow,
    const float* __restrict__ ln2, const float* __restrict__ rw,
    const float* __restrict__ gw, const float* __restrict__ uw,
    const float* __restrict__ dw, const float* __restrict__ flw,
    const float* __restrict__ sw, float* __restrict__ out,
    float* __restrict__ wsf, unsigned* __restrict__ bar) {
  __shared__ float xs[512];
  __shared__ float rbuf[4];
  const int tid = threadIdx.x;
  const int bid = blockIdx.x;

  float* h1    = wsf;                                   // [8][1024]
  float* Vp    = wsf + 8192;                            // [KSV][8][1024]
  float* Op    = Vp + (size_t)KSV * 8 * D;              // [KSV][8][1024]
  float* xr    = Op + (size_t)KSV * 8 * D;              // [8][1024]
  float* h2    = xr + 8192;                             // [8][1024]
  float* tw8   = h2 + 8192;                             // [8]
  int*   sel8  = (int*)(tw8 + 8);                       // [8]
  float* Pgu   = tw8 + 16;                              // [KS5][4][8][F]
  float* Dp    = Pgu + (size_t)KS5 * 4 * 8 * F;         // [KS6][2][8][1024]
  float* x2    = Dp + (size_t)KS6 * 2 * 8 * D;          // [8][1024]
  float* psq   = x2 + 8192;                             // [32]
  float* dummy = psq + 32;                              // [256] anti-DCE sink

  // ---- phase 1: h1[b] = rmsnorm(hidden[b,0,:], ln1) ----
  if (bid < 8) {
    int idx = tid * 4;
    float4 x = LD4(hs + (size_t)bid * S * D + idx);
    float ss = x.x*x.x + x.y*x.y + x.z*x.z + x.w*x.w;
    float tot = block_sum256(ss, rbuf);
    float sc = rsqrtf(tot * (1.f / (float)D) + 1e-6f);
    float4 wv = LD4(ln1 + idx);
    float4 o;
    o.x = x.x*sc*wv.x; o.y = x.y*sc*wv.y; o.z = x.z*sc*wv.z; o.w = x.w*sc*wv.w;
    *(float4*)(h1 + bid * D + idx) = o;
  }
  gsync(bar, NBLK * 1);

  float4 pref = {0,0,0,0};   // LLC-prefetch accumulator (idle blocks, phases 2-3)

  // ---- phase 2: Vp split-K partials of h1 @ v_w (64 blocks) ----
  if (bid < KSV) {
    int i0 = bid * CHV;
    if (tid < 128) xs[tid] = h1[(tid >> 4) * D + i0 + (tid & 15)];
    __syncthreads();
    int j = tid * 4;
    mv16((const float4*)(vw + (size_t)i0 * D + j), Vp + (size_t)bid * 8 * D, xs, j);
  } else {
    // 192 idle blocks: stream 64 KB each of gate_w into LLC (HBM otherwise idle)
    const float4* src = (const float4*)gw + (size_t)(bid - 64) * 4096 + tid;
    #pragma unroll
    for (int t = 0; t < 16; t++) {
      float4 v = src[(size_t)t * 256];
      pref.x += v.x; pref.y += v.y; pref.z += v.z; pref.w += v.w;
    }
  }
  gsync(bar, NBLK * 2);

  // ---- phase 3: reduce Vp slice -> xs, then Op partials of v0 @ o_w ----
  if (bid < KSV) {
    int i0 = bid * CHV;
    if (tid < 128) {
      int bb = tid >> 4, ii = tid & 15;
      float s = 0.f;
      #pragma unroll 8
      for (int p = 0; p < KSV; p++) s += Vp[((size_t)p * 8 + bb) * D + i0 + ii];
      xs[bb * 16 + ii] = s;
    }
    __syncthreads();
    int j = tid * 4;
    mv16((const float4*)(ow + (size_t)i0 * D + j), Op + (size_t)bid * 8 * D, xs, j);
  } else {
    // 64 KB each of up_w into LLC
    const float4* src = (const float4*)uw + (size_t)(bid - 64) * 4096 + tid;
    #pragma unroll
    for (int t = 0; t < 16; t++) {
      float4 v = src[(size_t)t * 256];
      pref.x += v.x; pref.y += v.y; pref.z += v.z; pref.w += v.w;
    }
    float tchk = pref.x + pref.y + pref.z + pref.w;
    if (tchk > 1e30f) dummy[bid] = tchk;   // opaque: keeps prefetch loads live
  }
  gsync(bar, NBLK * 3);

  // ---- phase 4: xr = hs + attn_out; h2 = rmsnorm(xr, ln2); router top-1 ----
  if (bid < 8) {
    int idx = tid * 4;
    float4 x = LD4(hs + (size_t)bid * S * D + idx);
    #pragma unroll 8
    for (int p = 0; p < KSV; p++) {
      float4 v = LD4(Op + ((size_t)p * 8 + bid) * D + idx);
      x.x += v.x; x.y += v.y; x.z += v.z; x.w += v.w;
    }
    *(float4*)(xr + bid * D + idx) = x;
    float ss = x.x*x.x + x.y*x.y + x.z*x.z + x.w*x.w;
    float tot = block_sum256(ss, rbuf);
    float sc = rsqrtf(tot * (1.f / (float)D) + 1e-6f);
    float4 wv = LD4(ln2 + idx);
    float4 h;
    h.x = x.x*sc*wv.x; h.y = x.y*sc*wv.y; h.z = x.z*sc*wv.z; h.w = x.w*sc*wv.w;
    *(float4*)(h2 + bid * D + idx) = h;
    float r0 = h.x * rw[idx * 2]     + h.y * rw[(idx + 1) * 2] +
               h.z * rw[(idx + 2) * 2] + h.w * rw[(idx + 3) * 2];
    float r1 = h.x * rw[idx * 2 + 1]     + h.y * rw[(idx + 1) * 2 + 1] +
               h.z * rw[(idx + 2) * 2 + 1] + h.w * rw[(idx + 3) * 2 + 1];
    r0 = block_sum256(r0, rbuf);
    r1 = block_sum256(r1, rbuf);
    if (tid == 0) {
      float m = fmaxf(r0, r1);
      float e0 = __expf(r0 - m), e1 = __expf(r1 - m);
      float inv = 1.f / (e0 + e1);
      float p0 = e0 * inv, p1 = e1 * inv;
      tw8[bid] = fmaxf(p0, p1);
      sel8[bid] = (p1 > p0) ? 1 : 0;
    }
  }
  gsync(bar, NBLK * 4);

  // ---- phase 5: gate/up split-K partials (224 blocks: 14 col-tiles x 16 k-chunks) ----
  if (bid < 14 * KS5) {
    int kc = bid & 15, colt = bid >> 4;
    int i0 = kc * CH5;
    { int bb = tid >> 6, r = tid & 63;
      xs[tid]       = h2[bb * D + i0 + r];
      xs[tid + 256] = h2[(bb + 4) * D + i0 + r]; }
    __syncthreads();
    int c = colt * 1024 + tid * 4;     // flattened col over 4 matrices (4*F)
    int m = c / F;                     // 0:gate e0, 1:gate e1, 2:up e0, 3:up e1
    int j = c - m * F;
    const float* base = (m < 2 ? gw : uw) + (size_t)(m & 1) * D * F;
    const float4* Wp = (const float4*)(base + (size_t)i0 * F + j);
    const int st = F / 4;
    float4 acc0 = {0,0,0,0}, acc1 = {0,0,0,0}, acc2 = {0,0,0,0}, acc3 = {0,0,0,0};
    float4 acc4 = {0,0,0,0}, acc5 = {0,0,0,0}, acc6 = {0,0,0,0}, acc7 = {0,0,0,0};
    float4 w0 = Wp[0*st], w1 = Wp[1*st], w2 = Wp[2*st], w3 = Wp[3*st];
    float4 w4 = Wp[4*st], w5 = Wp[5*st], w6 = Wp[6*st], w7 = Wp[7*st];
    Wp += 8 * st;
    #pragma unroll
    for (int t = 0; t < CH5 / 8 - 1; t++) {
      float4 n0 = Wp[0*st], n1 = Wp[1*st], n2 = Wp[2*st], n3 = Wp[3*st];
      float4 n4 = Wp[4*st], n5 = Wp[5*st], n6 = Wp[6*st], n7 = Wp[7*st];
      Wp += 8 * st;
      ALL8(xs, CH5, t * 8);
      w0 = n0; w1 = n1; w2 = n2; w3 = n3; w4 = n4; w5 = n5; w6 = n6; w7 = n7;
    }
    ALL8(xs, CH5, CH5 - 8);
    #define GU_ST(bb, ACC) \
      *(float4*)(Pgu + (((size_t)kc * 4 + m) * 8 + (bb)) * F + j) = ACC;
    GU_ST(0, acc0) GU_ST(1, acc1) GU_ST(2, acc2) GU_ST(3, acc3)
    GU_ST(4, acc4) GU_ST(5, acc5) GU_ST(6, acc6) GU_ST(7, acc7)
    #undef GU_ST
  }
  gsync(bar, NBLK * 5);

  // ---- phase 6: silu-reduce Pgu slice -> xs, then down split-K partials ----
  if (bid < 2 * KS6) {
    int e = bid & 1, ch = bid >> 1, i0 = ch * CH6;
    { int bb = tid >> 5, ii = tid & 31;
      float ga = 0.f, ua = 0.f;
      #pragma unroll
      for (int kc = 0; kc < KS5; kc++) {
        ga += Pgu[(((size_t)kc * 4 + e)     * 8 + bb) * F + i0 + ii];
        ua += Pgu[(((size_t)kc * 4 + 2 + e) * 8 + bb) * F + i0 + ii];
      }
      xs[bb * CH6 + ii] = (ga / (1.f + __expf(-ga))) * ua; }
    __syncthreads();
    int j = tid * 4;
    const float4* Wp = (const float4*)(dw + (size_t)e * F * D + (size_t)i0 * D + j);
    const int st = D / 4;
    float4 acc0 = {0,0,0,0}, acc1 = {0,0,0,0}, acc2 = {0,0,0,0}, acc3 = {0,0,0,0};
    float4 acc4 = {0,0,0,0}, acc5 = {0,0,0,0}, acc6 = {0,0,0,0}, acc7 = {0,0,0,0};
    float4 w0 = Wp[0*st], w1 = Wp[1*st], w2 = Wp[2*st], w3 = Wp[3*st];
    float4 w4 = Wp[4*st], w5 = Wp[5*st], w6 = Wp[6*st], w7 = Wp[7*st];
    Wp += 8 * st;
    #pragma unroll
    for (int t = 0; t < CH6 / 8 - 1; t++) {
      float4 n0 = Wp[0*st], n1 = Wp[1*st], n2 = Wp[2*st], n3 = Wp[3*st];
      float4 n4 = Wp[4*st], n5 = Wp[5*st], n6 = Wp[6*st], n7 = Wp[7*st];
      Wp += 8 * st;
      ALL8(xs, CH6, t * 8);
      w0 = n0; w1 = n1; w2 = n2; w3 = n3; w4 = n4; w5 = n5; w6 = n6; w7 = n7;
    }
    ALL8(xs, CH6, CH6 - 8);
    #define DN_ST(bb, ACC) \
      *(float4*)(Dp + (((size_t)ch * 2 + e) * 8 + (bb)) * D + j) = ACC;
    DN_ST(0, acc0) DN_ST(1, acc1) DN_ST(2, acc2) DN_ST(3, acc3)
    DN_ST(4, acc4) DN_ST(5, acc5) DN_ST(6, acc6) DN_ST(7, acc7)
    #undef DN_ST
  }
  gsync(bar, NBLK * 6);

  // ---- phase 7: x2 = xr + top_w * sum_p Dp[p][sel]; per-block partial sumsq ----
  if (bid < 32) {
    int gid = bid * 256 + tid;
    int bb = gid >> 10, col = gid & 1023;
    int e = sel8[bb];
    float tw = tw8[bb];
    float s = 0.f;
    #pragma unroll 8
    for (int p = 0; p < KS6; p++) s += Dp[(((size_t)p * 2 + e) * 8 + bb) * D + col];
    float v = xr[bb * D + col] + tw * s;
    x2[gid] = v;
    float ps = block_sum256(v * v, rbuf);
    if (tid == 0) psq[bid] = ps;       // bid == bb*4 + quarter
  }
  gsync(bar, NBLK * 7);

  // ---- phase 8: final rmsnorm + score head ----
  if (bid < 8) {
    int idx = tid * 4;
    float tot = psq[bid * 4] + psq[bid * 4 + 1] + psq[bid * 4 + 2] + psq[bid * 4 + 3];
    float sc = rsqrtf(tot * (1.f / (float)D) + 1e-6f);
    float4 x = LD4(x2 + bid * D + idx);
    float4 wv = LD4(flw + idx);
    float n0 = x.x*sc*wv.x, n1 = x.y*sc*wv.y, n2 = x.z*sc*wv.z, n3 = x.w*sc*wv.w;
    float l0 = n0 * sw[idx * 2]     + n1 * sw[(idx + 1) * 2] +
               n2 * sw[(idx + 2) * 2] + n3 * sw[(idx + 3) * 2];
    float l1 = n0 * sw[idx * 2 + 1]     + n1 * sw[(idx + 1) * 2 + 1] +
               n2 * sw[(idx + 2) * 2 + 1] + n3 * sw[(idx + 3) * 2 + 1];
    l0 = block_sum256(l0, rbuf);
    l1 = block_sum256(l1, rbuf);
    if (tid == 0) { out[bid * 2 + 0] = l0; out[bid * 2 + 1] = l1; }
  }
}

extern "C" void kernel_launch(void* const* d_in, const int* in_sizes, int n_in,
                              void* d_out, int out_size, void* d_ws, size_t ws_size,
                              hipStream_t stream) {
  const float* hs  = (const float*)d_in[0];
  const float* ln1 = (const float*)d_in[1];
  // d_in[2]=q_w, d_in[3]=k_w: dead — token-0 causal attention only needs V.
  const float* vw  = (const float*)d_in[4];
  const float* ow  = (const float*)d_in[5];
  const float* ln2 = (const float*)d_in[6];
  const float* rw  = (const float*)d_in[7];
  const float* gw  = (const float*)d_in[8];
  const float* uw  = (const float*)d_in[9];
  const float* dw  = (const float*)d_in[10];
  const float* flw = (const float*)d_in[11];
  const float* sw  = (const float*)d_in[12];

  unsigned* bar = (unsigned*)d_ws;          // first 256 B: grid-barrier counter
  float* wsf = (float*)d_ws + 64;           // data region (~27 MB used)

  // ws is poisoned between iterations: the barrier counter must be zeroed on
  // the stream every launch (graph-captured as a memset node).
  (void)hipMemsetAsync(d_ws, 0, 256, stream);
  hipLaunchKernelGGL(k_fused, dim3(NBLK), dim3(256), 0, stream,
                     hs, ln1, vw, ow, ln2, rw, gw, uw, dw, flw, sw,
                     (float*)d_out, wsf, bar);
}

// Round 4
// 252.169 us; speedup vs baseline: 1.5014x; 1.1711x over previous
//
#include <hip/hip_runtime.h>
#include <math.h>

#define B 8
#define S 1024
#define D 1024
#define F 3584

#define NBLK 256   // grid size; <= CU count -> co-residency guaranteed by capacity
#define KSV 64     // split-K chunks for 1024x1024 matvecs (16 rows each)
#define CHV 16
#define KS5 16     // gate/up split-K chunks (64 rows each)
#define CH5 64
#define KS6 112    // down split-K chunks (32 rows each)
#define CH6 32

#define LD4(p) (*(const float4*)(p))
#define FMA4(A, s, W) { (A).x += (s)*(W).x; (A).y += (s)*(W).y; (A).z += (s)*(W).z; (A).w += (s)*(W).w; }

// 8-row FMA step for one token-batch bb against weight regs w0..w7
#define BB8(bb, ACC, XS, CH, koff) { \
  float4 xa = LD4((XS) + (bb)*(CH) + (koff)); \
  float4 xb = LD4((XS) + (bb)*(CH) + (koff) + 4); \
  FMA4(ACC, xa.x, w0); FMA4(ACC, xa.y, w1); FMA4(ACC, xa.z, w2); FMA4(ACC, xa.w, w3); \
  FMA4(ACC, xb.x, w4); FMA4(ACC, xb.y, w5); FMA4(ACC, xb.z, w6); FMA4(ACC, xb.w, w7); }

#define ALL8(XS, CH, koff) \
  BB8(0, acc0, XS, CH, koff) BB8(1, acc1, XS, CH, koff) \
  BB8(2, acc2, XS, CH, koff) BB8(3, acc3, XS, CH, koff) \
  BB8(4, acc4, XS, CH, koff) BB8(5, acc5, XS, CH, koff) \
  BB8(6, acc6, XS, CH, koff) BB8(7, acc7, XS, CH, koff)

// ---------------- block-wide sum for 256-thread blocks ----------------
__device__ __forceinline__ float block_sum256(float v, volatile float* buf) {
  #pragma unroll
  for (int o = 32; o; o >>= 1) v += __shfl_down(v, o);   // wave64 reduce
  __syncthreads();
  if ((threadIdx.x & 63) == 0) buf[threadIdx.x >> 6] = v;
  __syncthreads();
  return buf[0] + buf[1] + buf[2] + buf[3];
}

// ---------------- grid barrier v3: decoupled arrival / release ----------------
// Round-3 post-mortem: a single counter line used for BOTH arrival RMWs and
// ~255 blocks' polling saturates one LLC slice's request queue; arrivals queue
// behind the poll stream -> ~22 us per barrier. v3 decouples them:
//   - arrivals fetch_add a counter line (contends only with 255 other adds),
//   - the block whose add returns tgt-1 release-stores a per-phase FLAG on its
//     own 128 B line,
//   - everyone else polls the flag (read-only; no RMW behind it) with
//     s_sleep(8) (~512 cy) backoff, then one ACQUIRE load for visibility.
// HB chain: producer release-add -> releaser acq_rel RMW (release sequence)
// -> releaser release-store flag -> poller acquire-load flag.
// Counter + flags live in the first 1 KiB of ws, memset to 0 each launch.
__device__ __forceinline__ void gsync(unsigned* bar, int phase) {
  __syncthreads();
  if (threadIdx.x == 0) {
    unsigned* flag = bar + 32 * phase;     // one 128 B line per phase
    unsigned old = __hip_atomic_fetch_add(bar, 1u, __ATOMIC_ACQ_REL,
                                          __HIP_MEMORY_SCOPE_AGENT);
    if (old == (unsigned)(NBLK * phase) - 1u) {
      __hip_atomic_store(flag, 1u, __ATOMIC_RELEASE, __HIP_MEMORY_SCOPE_AGENT);
    } else {
      while (__hip_atomic_load(flag, __ATOMIC_RELAXED,
                               __HIP_MEMORY_SCOPE_AGENT) == 0u)
        __builtin_amdgcn_s_sleep(8);
      (void)__hip_atomic_load(flag, __ATOMIC_ACQUIRE, __HIP_MEMORY_SCOPE_AGENT);
    }
  }
  __syncthreads();
}

// 16-row x 1024-col x 8-token matvec step (phases 2 and 3).
__device__ __forceinline__ void mv16(const float4* __restrict__ Wp,
                                     float* __restrict__ Pout,
                                     const float* xs, int j) {
  const int st = D / 4;
  float4 acc0 = {0,0,0,0}, acc1 = {0,0,0,0}, acc2 = {0,0,0,0}, acc3 = {0,0,0,0};
  float4 acc4 = {0,0,0,0}, acc5 = {0,0,0,0}, acc6 = {0,0,0,0}, acc7 = {0,0,0,0};
  float4 w0 = Wp[0*st], w1 = Wp[1*st], w2 = Wp[2*st], w3 = Wp[3*st];
  float4 w4 = Wp[4*st], w5 = Wp[5*st], w6 = Wp[6*st], w7 = Wp[7*st];
  float4 v0 = Wp[8*st], v1 = Wp[9*st], v2 = Wp[10*st], v3 = Wp[11*st];
  float4 v4 = Wp[12*st], v5 = Wp[13*st], v6 = Wp[14*st], v7 = Wp[15*st];
  ALL8(xs, CHV, 0);
  w0 = v0; w1 = v1; w2 = v2; w3 = v3; w4 = v4; w5 = v5; w6 = v6; w7 = v7;
  ALL8(xs, CHV, 8);
  *(float4*)(Pout + 0*(size_t)D + j) = acc0;
  *(float4*)(Pout + 1*(size_t)D + j) = acc1;
  *(float4*)(Pout + 2*(size_t)D + j) = acc2;
  *(float4*)(Pout + 3*(size_t)D + j) = acc3;
  *(float4*)(Pout + 4*(size_t)D + j) = acc4;
  *(float4*)(Pout + 5*(size_t)D + j) = acc5;
  *(float4*)(Pout + 6*(size_t)D + j) = acc6;
  *(float4*)(Pout + 7*(size_t)D + j) = acc7;
}

// One fused kernel: 7 phases, 6 grid barriers.
__global__ __launch_bounds__(256, 1) void k_fused(
    const float* __restrict__ hs, const float* __restrict__ ln1,
    const float* __restrict__ vw, const float* __restrict__ ow,
    const float* __restrict__ ln2, const float* __restrict__ rw,
    const float* __restrict__ gw, const float* __restrict__ uw,
    const float* __restrict__ dw, const float* __restrict__ flw,
    const float* __restrict__ sw, float* __restrict__ out,
    float* __restrict__ wsf, unsigned* __restrict__ bar) {
  __shared__ float xs[512];
  __shared__ float rbuf[4];
  const int tid = threadIdx.x;
  const int bid = blockIdx.x;

  float* h1    = wsf;                                   // [8][1024]
  float* Vp    = wsf + 8192;                            // [KSV][8][1024]
  float* Op    = Vp + (size_t)KSV * 8 * D;              // [KSV][8][1024]
  float* xr    = Op + (size_t)KSV * 8 * D;              // [8][1024]
  float* h2    = xr + 8192;                             // [8][1024]
  float* tw8   = h2 + 8192;                             // [8]
  int*   sel8  = (int*)(tw8 + 8);                       // [8]
  float* Pgu   = tw8 + 16;                              // [KS5][4][8][F]
  float* Dp    = Pgu + (size_t)KS5 * 4 * 8 * F;         // [KS6][2][8][1024]
  float* dummy = Dp + (size_t)KS6 * 2 * 8 * D;          // [256] anti-DCE sink

  // ---- phase 1: h1[b] = rmsnorm(hidden[b,0,:], ln1) ----
  if (bid < 8) {
    int idx = tid * 4;
    float4 x = LD4(hs + (size_t)bid * S * D + idx);
    float ss = x.x*x.x + x.y*x.y + x.z*x.z + x.w*x.w;
    float tot = block_sum256(ss, rbuf);
    float sc = rsqrtf(tot * (1.f / (float)D) + 1e-6f);
    float4 wv = LD4(ln1 + idx);
    float4 o;
    o.x = x.x*sc*wv.x; o.y = x.y*sc*wv.y; o.z = x.z*sc*wv.z; o.w = x.w*sc*wv.w;
    *(float4*)(h1 + bid * D + idx) = o;
  }
  gsync(bar, 1);

  float4 pref = {0,0,0,0};   // LLC-prefetch accumulator (idle blocks, phases 2-3)

  // ---- phase 2: Vp split-K partials of h1 @ v_w (64 blocks) ----
  if (bid < KSV) {
    int i0 = bid * CHV;
    if (tid < 128) xs[tid] = h1[(tid >> 4) * D + i0 + (tid & 15)];
    __syncthreads();
    int j = tid * 4;
    mv16((const float4*)(vw + (size_t)i0 * D + j), Vp + (size_t)bid * 8 * D, xs, j);
  } else {
    // 192 idle blocks: stream 64 KB each of gate_w into LLC (HBM otherwise idle)
    const float4* src = (const float4*)gw + (size_t)(bid - 64) * 4096 + tid;
    #pragma unroll
    for (int t = 0; t < 16; t++) {
      float4 v = src[(size_t)t * 256];
      pref.x += v.x; pref.y += v.y; pref.z += v.z; pref.w += v.w;
    }
  }
  gsync(bar, 2);

  // ---- phase 3: reduce Vp slice -> xs, then Op partials of v0 @ o_w ----
  if (bid < KSV) {
    int i0 = bid * CHV;
    if (tid < 128) {
      int bb = tid >> 4, ii = tid & 15;
      float s = 0.f;
      #pragma unroll 8
      for (int p = 0; p < KSV; p++) s += Vp[((size_t)p * 8 + bb) * D + i0 + ii];
      xs[bb * 16 + ii] = s;
    }
    __syncthreads();
    int j = tid * 4;
    mv16((const float4*)(ow + (size_t)i0 * D + j), Op + (size_t)bid * 8 * D, xs, j);
  } else {
    // 64 KB each of up_w into LLC
    const float4* src = (const float4*)uw + (size_t)(bid - 64) * 4096 + tid;
    #pragma unroll
    for (int t = 0; t < 16; t++) {
      float4 v = src[(size_t)t * 256];
      pref.x += v.x; pref.y += v.y; pref.z += v.z; pref.w += v.w;
    }
    float tchk = pref.x + pref.y + pref.z + pref.w;
    if (tchk > 1e30f) dummy[bid] = tchk;   // opaque: keeps prefetch loads live
  }
  gsync(bar, 3);

  // ---- phase 4: xr = hs + attn_out; h2 = rmsnorm(xr, ln2); router top-1 ----
  if (bid < 8) {
    int idx = tid * 4;
    float4 x = LD4(hs + (size_t)bid * S * D + idx);
    #pragma unroll 8
    for (int p = 0; p < KSV; p++) {
      float4 v = LD4(Op + ((size_t)p * 8 + bid) * D + idx);
      x.x += v.x; x.y += v.y; x.z += v.z; x.w += v.w;
    }
    *(float4*)(xr + bid * D + idx) = x;
    float ss = x.x*x.x + x.y*x.y + x.z*x.z + x.w*x.w;
    float tot = block_sum256(ss, rbuf);
    float sc = rsqrtf(tot * (1.f / (float)D) + 1e-6f);
    float4 wv = LD4(ln2 + idx);
    float4 h;
    h.x = x.x*sc*wv.x; h.y = x.y*sc*wv.y; h.z = x.z*sc*wv.z; h.w = x.w*sc*wv.w;
    *(float4*)(h2 + bid * D + idx) = h;
    float r0 = h.x * rw[idx * 2]     + h.y * rw[(idx + 1) * 2] +
               h.z * rw[(idx + 2) * 2] + h.w * rw[(idx + 3) * 2];
    float r1 = h.x * rw[idx * 2 + 1]     + h.y * rw[(idx + 1) * 2 + 1] +
               h.z * rw[(idx + 2) * 2 + 1] + h.w * rw[(idx + 3) * 2 + 1];
    r0 = block_sum256(r0, rbuf);
    r1 = block_sum256(r1, rbuf);
    if (tid == 0) {
      float m = fmaxf(r0, r1);
      float e0 = __expf(r0 - m), e1 = __expf(r1 - m);
      float inv = 1.f / (e0 + e1);
      float p0 = e0 * inv, p1 = e1 * inv;
      tw8[bid] = fmaxf(p0, p1);
      sel8[bid] = (p1 > p0) ? 1 : 0;
    }
  }
  gsync(bar, 4);

  // ---- phase 5: gate/up split-K partials (224 blocks: 14 col-tiles x 16 k-chunks) ----
  if (bid < 14 * KS5) {
    int kc = bid & 15, colt = bid >> 4;
    int i0 = kc * CH5;
    { int bb = tid >> 6, r = tid & 63;
      xs[tid]       = h2[bb * D + i0 + r];
      xs[tid + 256] = h2[(bb + 4) * D + i0 + r]; }
    __syncthreads();
    int c = colt * 1024 + tid * 4;     // flattened col over 4 matrices (4*F)
    int m = c / F;                     // 0:gate e0, 1:gate e1, 2:up e0, 3:up e1
    int j = c - m * F;
    const float* base = (m < 2 ? gw : uw) + (size_t)(m & 1) * D * F;
    const float4* Wp = (const float4*)(base + (size_t)i0 * F + j);
    const int st = F / 4;
    float4 acc0 = {0,0,0,0}, acc1 = {0,0,0,0}, acc2 = {0,0,0,0}, acc3 = {0,0,0,0};
    float4 acc4 = {0,0,0,0}, acc5 = {0,0,0,0}, acc6 = {0,0,0,0}, acc7 = {0,0,0,0};
    float4 w0 = Wp[0*st], w1 = Wp[1*st], w2 = Wp[2*st], w3 = Wp[3*st];
    float4 w4 = Wp[4*st], w5 = Wp[5*st], w6 = Wp[6*st], w7 = Wp[7*st];
    Wp += 8 * st;
    #pragma unroll
    for (int t = 0; t < CH5 / 8 - 1; t++) {
      float4 n0 = Wp[0*st], n1 = Wp[1*st], n2 = Wp[2*st], n3 = Wp[3*st];
      float4 n4 = Wp[4*st], n5 = Wp[5*st], n6 = Wp[6*st], n7 = Wp[7*st];
      Wp += 8 * st;
      ALL8(xs, CH5, t * 8);
      w0 = n0; w1 = n1; w2 = n2; w3 = n3; w4 = n4; w5 = n5; w6 = n6; w7 = n7;
    }
    ALL8(xs, CH5, CH5 - 8);
    #define GU_ST(bb, ACC) \
      *(float4*)(Pgu + (((size_t)kc * 4 + m) * 8 + (bb)) * F + j) = ACC;
    GU_ST(0, acc0) GU_ST(1, acc1) GU_ST(2, acc2) GU_ST(3, acc3)
    GU_ST(4, acc4) GU_ST(5, acc5) GU_ST(6, acc6) GU_ST(7, acc7)
    #undef GU_ST
  }
  gsync(bar, 5);

  // ---- phase 6: silu-reduce Pgu slice -> xs, then down split-K partials ----
  if (bid < 2 * KS6) {
    int e = bid & 1, ch = bid >> 1, i0 = ch * CH6;
    { int bb = tid >> 5, ii = tid & 31;
      float ga = 0.f, ua = 0.f;
      #pragma unroll
      for (int kc = 0; kc < KS5; kc++) {
        ga += Pgu[(((size_t)kc * 4 + e)     * 8 + bb) * F + i0 + ii];
        ua += Pgu[(((size_t)kc * 4 + 2 + e) * 8 + bb) * F + i0 + ii];
      }
      xs[bb * CH6 + ii] = (ga / (1.f + __expf(-ga))) * ua; }
    __syncthreads();
    int j = tid * 4;
    const float4* Wp = (const float4*)(dw + (size_t)e * F * D + (size_t)i0 * D + j);
    const int st = D / 4;
    float4 acc0 = {0,0,0,0}, acc1 = {0,0,0,0}, acc2 = {0,0,0,0}, acc3 = {0,0,0,0};
    float4 acc4 = {0,0,0,0}, acc5 = {0,0,0,0}, acc6 = {0,0,0,0}, acc7 = {0,0,0,0};
    float4 w0 = Wp[0*st], w1 = Wp[1*st], w2 = Wp[2*st], w3 = Wp[3*st];
    float4 w4 = Wp[4*st], w5 = Wp[5*st], w6 = Wp[6*st], w7 = Wp[7*st];
    Wp += 8 * st;
    #pragma unroll
    for (int t = 0; t < CH6 / 8 - 1; t++) {
      float4 n0 = Wp[0*st], n1 = Wp[1*st], n2 = Wp[2*st], n3 = Wp[3*st];
      float4 n4 = Wp[4*st], n5 = Wp[5*st], n6 = Wp[6*st], n7 = Wp[7*st];
      Wp += 8 * st;
      ALL8(xs, CH6, t * 8);
      w0 = n0; w1 = n1; w2 = n2; w3 = n3; w4 = n4; w5 = n5; w6 = n6; w7 = n7;
    }
    ALL8(xs, CH6, CH6 - 8);
    #define DN_ST(bb, ACC) \
      *(float4*)(Dp + (((size_t)ch * 2 + e) * 8 + (bb)) * D + j) = ACC;
    DN_ST(0, acc0) DN_ST(1, acc1) DN_ST(2, acc2) DN_ST(3, acc3)
    DN_ST(4, acc4) DN_ST(5, acc5) DN_ST(6, acc6) DN_ST(7, acc7)
    #undef DN_ST
  }
  gsync(bar, 6);

  // ---- phase 7 (merged old 7+8): residual + final rmsnorm + score head ----
  if (bid < 8) {
    int e = sel8[bid];
    float tw = tw8[bid];
    int idx = tid * 4;
    float4 y = {0,0,0,0};
    #pragma unroll 8
    for (int p = 0; p < KS6; p++) {
      float4 v = LD4(Dp + (((size_t)p * 2 + e) * 8 + bid) * D + idx);
      y.x += v.x; y.y += v.y; y.z += v.z; y.w += v.w;
    }
    float4 x = LD4(xr + bid * D + idx);
    x.x += tw * y.x; x.y += tw * y.y; x.z += tw * y.z; x.w += tw * y.w;
    float ss = x.x*x.x + x.y*x.y + x.z*x.z + x.w*x.w;
    float tot = block_sum256(ss, rbuf);
    float sc = rsqrtf(tot * (1.f / (float)D) + 1e-6f);
    float4 wv = LD4(flw + idx);
    float n0 = x.x*sc*wv.x, n1 = x.y*sc*wv.y, n2 = x.z*sc*wv.z, n3 = x.w*sc*wv.w;
    float l0 = n0 * sw[idx * 2]     + n1 * sw[(idx + 1) * 2] +
               n2 * sw[(idx + 2) * 2] + n3 * sw[(idx + 3) * 2];
    float l1 = n0 * sw[idx * 2 + 1]     + n1 * sw[(idx + 1) * 2 + 1] +
               n2 * sw[(idx + 2) * 2 + 1] + n3 * sw[(idx + 3) * 2 + 1];
    l0 = block_sum256(l0, rbuf);
    l1 = block_sum256(l1, rbuf);
    if (tid == 0) { out[bid * 2 + 0] = l0; out[bid * 2 + 1] = l1; }
  }
}

extern "C" void kernel_launch(void* const* d_in, const int* in_sizes, int n_in,
                              void* d_out, int out_size, void* d_ws, size_t ws_size,
                              hipStream_t stream) {
  const float* hs  = (const float*)d_in[0];
  const float* ln1 = (const float*)d_in[1];
  // d_in[2]=q_w, d_in[3]=k_w: dead — token-0 causal attention only needs V.
  const float* vw  = (const float*)d_in[4];
  const float* ow  = (const float*)d_in[5];
  const float* ln2 = (const float*)d_in[6];
  const float* rw  = (const float*)d_in[7];
  const float* gw  = (const float*)d_in[8];
  const float* uw  = (const float*)d_in[9];
  const float* dw  = (const float*)d_in[10];
  const float* flw = (const float*)d_in[11];
  const float* sw  = (const float*)d_in[12];

  unsigned* bar = (unsigned*)d_ws;          // first 1 KiB: counter + 6 flag lines
  float* wsf = (float*)d_ws + 256;          // data region (~27 MB used)

  // ws is poisoned between iterations: counter + flags must be zeroed on the
  // stream every launch (graph-captured as a memset node).
  (void)hipMemsetAsync(d_ws, 0, 1024, stream);
  hipLaunchKernelGGL(k_fused, dim3(NBLK), dim3(256), 0, stream,
                     hs, ln1, vw, ow, ln2, rw, gw, uw, dw, flw, sw,
                     (float*)d_out, wsf, bar);
}